// Round 2
// baseline (344.171 us; speedup 1.0000x reference)
//
#include <hip/hip_runtime.h>
#include <hip/hip_bf16.h>

#define BATCH    256
#define NU       300
#define LIN      608
#define FILT     19
#define LPOOL    84
#define POOL     7
#define HID      100
#define NCLS     50
#define EPS      1e-5f
#define UPB      3     // units per block in k_conv
#define ROWP     610   // padded LDS row (608 data + shift slack), even for b64 align

// ---------------------------------------------------------------------------
// Kernel 1: conv(4->300, k=19) + bias + BN + exp + maxpool(7)
//   exp(bn(.)) monotone (scale>0) -> pool raw conv, then one bn+exp.
//   x staged in LDS TWICE (shift 0 and 1 float) so each thread's window
//   start 7p is 8B-aligned in copy (7p&1): 13 ds_read_b64 per channel
//   instead of ~130 scalar reads. Window + acc stay in VGPRs (~50).
// ---------------------------------------------------------------------------
__global__ __launch_bounds__(256, 4)
void k_conv(const float* __restrict__ x, const float* __restrict__ w1,
            const float* __restrict__ b1, const float* __restrict__ g1,
            const float* __restrict__ be1, const float* __restrict__ m1,
            const float* __restrict__ v1, float* __restrict__ ypool)
{
    // xs[copy][c][ROWP]: copyS slot of x[m] is m+S
    __shared__ __align__(16) float xs[2 * 4 * ROWP];   // 19520 B
    __shared__ float wsh[UPB * 4 * FILT];              // 912 B
    __shared__ float s_sh[UPB], c_sh[UPB];

    const int tid = threadIdx.x;
    const int u0  = blockIdx.x * UPB;
    const int b   = blockIdx.y;

    // stage x[b]: one global read, two shifted LDS copies
    {
        const float* xg = x + (size_t)b * 4 * LIN;
        for (int i = tid; i < 4 * LIN; i += 256) {
            const float v = xg[i];
            const int c = i / LIN;
            const int m = i - c * LIN;
            xs[c * ROWP + m]                 = v;   // copy 0
            xs[4 * ROWP + c * ROWP + m + 1]  = v;   // copy 1, shifted
        }
    }
    for (int i = tid; i < UPB * 4 * FILT; i += 256)
        wsh[i] = w1[u0 * 4 * FILT + i];
    if (tid < UPB) {
        int u = u0 + tid;
        float s = g1[u] * rsqrtf(v1[u] + EPS);
        s_sh[tid] = s;
        c_sh[tid] = (b1[u] - m1[u]) * s + be1[u];
    }
    __syncthreads();

    if (tid < UPB * LPOOL) {
        const int ul = tid / LPOOL;
        const int p  = tid - ul * LPOOL;
        const int f0 = p * POOL;
        const int S  = f0 & 1;                 // which shifted copy
        const float* wp = &wsh[ul * 4 * FILT];
        // base of the aligned pair stream for this thread (per channel added later)
        const int pairBase = (f0 + S) >> 1;    // float2 index within row

        float acc[POOL];
#pragma unroll
        for (int j = 0; j < POOL; ++j) acc[j] = 0.f;

#pragma unroll
        for (int c = 0; c < 4; ++c) {
            const float2* pp =
                (const float2*)(xs + S * (4 * ROWP) + c * ROWP) + pairBase;
            float2 xv[13];
#pragma unroll
            for (int q = 0; q < 13; ++q) xv[q] = pp[q];
            // xw(i) = x[c][f0 + i]
#define XW(i) (((i) & 1) ? xv[(i) >> 1].y : xv[(i) >> 1].x)
#pragma unroll
            for (int k = 0; k < FILT; ++k) {
                const float w = wp[c * FILT + k];
#pragma unroll
                for (int j = 0; j < POOL; ++j)
                    acc[j] = fmaf(XW(k + j), w, acc[j]);
            }
#undef XW
        }
        float m = acc[0];
#pragma unroll
        for (int j = 1; j < POOL; ++j) m = fmaxf(m, acc[j]);

        const float out = __expf(fmaf(m, s_sh[ul], c_sh[ul]));
        ypool[((size_t)(u0 + ul) * LPOOL + p) * BATCH + b] = out;
    }
}

// ---------------------------------------------------------------------------
// Kernel 2: per-unit MLP 84 -> 100 (+BN+ReLU) -> 1 (+BN+ReLU)
//   grid (300 units, 4 batch-quarters); lane = batch, wave = o-stripe.
//   w2 rows read from wave-uniform addresses (scalarizable, no LDS staging,
//   only 4 floats live at a time); 4 partial sums break the serial chain;
//   4-wave partial-z reduce through 1KB LDS.
// ---------------------------------------------------------------------------
__global__ __launch_bounds__(256, 4)
void k_mlp(const float* __restrict__ ypool, const float* __restrict__ w2,
           const float* __restrict__ b2, const float* __restrict__ g2,
           const float* __restrict__ be2, const float* __restrict__ m2,
           const float* __restrict__ v2, const float* __restrict__ w3,
           const float* __restrict__ b3, const float* __restrict__ g3,
           const float* __restrict__ be3, const float* __restrict__ m3,
           const float* __restrict__ v3, float* __restrict__ zbuf)
{
    __shared__ float zp[4][64];

    const int u    = blockIdx.x;
    const int bq   = blockIdx.y;
    const int wave = threadIdx.x >> 6;
    const int lane = threadIdx.x & 63;
    const int b    = bq * 64 + lane;

    // y row for this batch element: 84 VGPRs, coalesced (256B per load)
    float yreg[LPOOL];
    const float* yp = ypool + (size_t)u * LPOOL * BATCH + b;
#pragma unroll
    for (int f = 0; f < LPOOL; ++f) yreg[f] = yp[f * BATCH];

    float z = 0.f;
#pragma unroll 1
    for (int o = wave; o < HID; o += 4) {
        const int uo = u * HID + o;
        const float4* w2v = (const float4*)(w2 + (size_t)uo * LPOOL); // 336B rows: 16B aligned
        float h0 = 0.f, h1 = 0.f, h2 = 0.f, h3 = 0.f;
#pragma unroll
        for (int q = 0; q < LPOOL / 4; ++q) {
            const float4 wv = w2v[q];
            h0 = fmaf(yreg[4 * q + 0], wv.x, h0);
            h1 = fmaf(yreg[4 * q + 1], wv.y, h1);
            h2 = fmaf(yreg[4 * q + 2], wv.z, h2);
            h3 = fmaf(yreg[4 * q + 3], wv.w, h3);
        }
        float h = (h0 + h1) + (h2 + h3);
        const float s2 = g2[uo] * rsqrtf(v2[uo] + EPS);
        const float c2 = (b2[uo] - m2[uo]) * s2 + be2[uo];
        h = fmaxf(fmaf(h, s2, c2), 0.f);
        z = fmaf(h, w3[uo], z);
    }

    zp[wave][lane] = z;
    __syncthreads();

    if (threadIdx.x < 64) {
        float zz = (zp[0][lane] + zp[1][lane]) + (zp[2][lane] + zp[3][lane]);
        const float s3 = g3[u] * rsqrtf(v3[u] + EPS);
        const float c3 = (b3[u] - m3[u]) * s3 + be3[u];
        zz = fmaxf(fmaf(zz, s3, c3), 0.f);
        zbuf[(size_t)u * BATCH + b] = zz;
    }
}

// ---------------------------------------------------------------------------
// Kernel 3: final linear 300 -> 50.  grid = 50, thread = batch.
//   wf reads wave-uniform (scalar path); 4 independent accumulators so the
//   zbuf loads pipeline instead of serializing on one FMA chain.
// ---------------------------------------------------------------------------
__global__ __launch_bounds__(256, 4)
void k_final(const float* __restrict__ zbuf, const float* __restrict__ wf,
             const float* __restrict__ bf, float* __restrict__ out)
{
    const int n = blockIdx.x;
    const int b = threadIdx.x;
    float a0 = 0.f, a1 = 0.f, a2 = 0.f, a3 = 0.f;
#pragma unroll 5
    for (int u = 0; u < NU; u += 4) {
        a0 = fmaf(zbuf[(size_t)(u + 0) * BATCH + b], wf[n * NU + u + 0], a0);
        a1 = fmaf(zbuf[(size_t)(u + 1) * BATCH + b], wf[n * NU + u + 1], a1);
        a2 = fmaf(zbuf[(size_t)(u + 2) * BATCH + b], wf[n * NU + u + 2], a2);
        a3 = fmaf(zbuf[(size_t)(u + 3) * BATCH + b], wf[n * NU + u + 3], a3);
    }
    out[(size_t)b * NCLS + n] = (a0 + a1) + (a2 + a3) + bf[n];
}

extern "C" void kernel_launch(void* const* d_in, const int* in_sizes, int n_in,
                              void* d_out, int out_size, void* d_ws, size_t ws_size,
                              hipStream_t stream)
{
    const float* x   = (const float*)d_in[0];
    const float* w1  = (const float*)d_in[1];
    const float* b1  = (const float*)d_in[2];
    const float* g1  = (const float*)d_in[3];
    const float* be1 = (const float*)d_in[4];
    const float* m1  = (const float*)d_in[5];
    const float* v1  = (const float*)d_in[6];
    const float* w2  = (const float*)d_in[7];
    const float* b2  = (const float*)d_in[8];
    const float* g2  = (const float*)d_in[9];
    const float* be2 = (const float*)d_in[10];
    const float* m2  = (const float*)d_in[11];
    const float* v2  = (const float*)d_in[12];
    const float* w3  = (const float*)d_in[13];
    const float* b3  = (const float*)d_in[14];
    const float* g3  = (const float*)d_in[15];
    const float* be3 = (const float*)d_in[16];
    const float* m3  = (const float*)d_in[17];
    const float* v3  = (const float*)d_in[18];
    const float* wf  = (const float*)d_in[19];
    const float* bf  = (const float*)d_in[20];

    float* ypool = (float*)d_ws;                                // 300*84*256 fp32 = 25.8 MB
    float* zbuf  = ypool + (size_t)NU * LPOOL * BATCH;          // 300*256 fp32

    dim3 gc(NU / UPB, BATCH);
    k_conv<<<gc, 256, 0, stream>>>(x, w1, b1, g1, be1, m1, v1, ypool);
    dim3 gm(NU, BATCH / 64);
    k_mlp<<<gm, 256, 0, stream>>>(ypool, w2, b2, g2, be2, m2, v2,
                                  w3, b3, g3, be3, m3, v3, zbuf);
    k_final<<<NCLS, 256, 0, stream>>>(zbuf, wf, bf, (float*)d_out);
}

// Round 3
// 214.653 us; speedup vs baseline: 1.6034x; 1.6034x over previous
//
#include <hip/hip_runtime.h>
#include <hip/hip_bf16.h>

#define BATCH    256
#define NU       300
#define LIN      608
#define FILT     19
#define LPOOL    84
#define POOL     7
#define HID      100
#define NCLS     50
#define EPS      1e-5f
#define UPB      3     // units per block in k_conv
#define KP       96    // stage-2 K padded (84 -> 96 = 3 x 32)
#define NP       112   // stage-2 N padded (100 -> 112 = 7 x 16)
#define LDK      104   // LDS row stride in shorts (96 + 8 pad: 2-way bank alias only)

typedef __attribute__((ext_vector_type(8))) short short8;   // 8 bf16 (4 VGPRs)
typedef __attribute__((ext_vector_type(4))) float float4v;  // MFMA acc

__device__ __forceinline__ unsigned short f2bf(float f) {
    unsigned u = __float_as_uint(f);
    u += 0x7fffu + ((u >> 16) & 1u);       // round-to-nearest-even
    return (unsigned short)(u >> 16);
}

// ---------------------------------------------------------------------------
// Kernel 1: conv(4->300, k=19) + bias + BN + exp + maxpool(7)  [R1 structure]
//   exp(bn(.)) monotone (scale>0) -> pool raw conv, then one bn+exp.
//   Output: bf16 ypool[u][b][KP], k-contiguous, zero-padded p in [84,96)
//   so k_mlp's MFMA A-fragments are direct 16B LDS rows.
// ---------------------------------------------------------------------------
__global__ __launch_bounds__(256, 4)
void k_conv(const float* __restrict__ x, const float* __restrict__ w1,
            const float* __restrict__ b1, const float* __restrict__ g1,
            const float* __restrict__ be1, const float* __restrict__ m1,
            const float* __restrict__ v1, unsigned short* __restrict__ ypool)
{
    __shared__ __align__(16) float xs[4 * LIN];     // 9728 B
    __shared__ float wsh[UPB * 4 * FILT];           // 912 B
    __shared__ float s_sh[UPB], c_sh[UPB];

    const int tid = threadIdx.x;
    const int u0  = blockIdx.x * UPB;
    const int b   = blockIdx.y;

    {
        const float4* xg = (const float4*)(x + (size_t)b * 4 * LIN);
        float4* xd = (float4*)xs;
        for (int i = tid; i < (4 * LIN) / 4; i += 256) xd[i] = xg[i];
    }
    for (int i = tid; i < UPB * 4 * FILT; i += 256)
        wsh[i] = w1[u0 * 4 * FILT + i];
    if (tid < UPB) {
        int u = u0 + tid;
        float s = g1[u] * rsqrtf(v1[u] + EPS);
        s_sh[tid] = s;
        c_sh[tid] = (b1[u] - m1[u]) * s + be1[u];
    }
    __syncthreads();

    if (tid < UPB * LPOOL) {
        const int ul = tid / LPOOL;
        const int p  = tid - ul * LPOOL;
        const int base = p * POOL;
        const float* wp = &wsh[ul * 4 * FILT];

        float acc[POOL];
#pragma unroll
        for (int j = 0; j < POOL; ++j) acc[j] = 0.f;

#pragma unroll
        for (int c = 0; c < 4; ++c) {
            float xr[POOL + FILT - 1];
#pragma unroll
            for (int i = 0; i < POOL + FILT - 1; ++i)
                xr[i] = xs[c * LIN + base + i];
#pragma unroll
            for (int k = 0; k < FILT; ++k) {
                const float w = wp[c * FILT + k];
#pragma unroll
                for (int j = 0; j < POOL; ++j)
                    acc[j] = fmaf(xr[k + j], w, acc[j]);
            }
        }
        float m = acc[0];
#pragma unroll
        for (int j = 1; j < POOL; ++j) m = fmaxf(m, acc[j]);

        const float out = __expf(fmaf(m, s_sh[ul], c_sh[ul]));
        ypool[((size_t)(u0 + ul) * BATCH + b) * KP + p] = f2bf(out);
    } else {
        // tid in [252,256): zero-fill K-pad slots p in [84,96) for all UPB units
        for (int i = tid - UPB * LPOOL; i < UPB * (KP - LPOOL); i += 256 - UPB * LPOOL) {
            const int ul = i / (KP - LPOOL);
            const int p  = LPOOL + i % (KP - LPOOL);
            ypool[((size_t)(u0 + ul) * BATCH + b) * KP + p] = 0;
        }
    }
}

// ---------------------------------------------------------------------------
// Kernel 2: per-unit MLP 84->100 (+BN+ReLU) ->1 (+BN+ReLU), bf16 MFMA.
//   grid (300 units, 4 batch-quarters), 4 waves/block.
//   A = Y_u [64 batch x 96 k] bf16 (from ypool), B = w2_u [112 n x 96 k] bf16
//   (cvt at staging). Wave w owns M-tile w: 7 N-tiles x 3 K-steps = 21 MFMAs.
//   Epilogue fuses BN2+ReLU+w3 per D-element, shfl-xor reduce over 16 cols,
//   BN3+ReLU -> zbuf[u][b].
// ---------------------------------------------------------------------------
__global__ __launch_bounds__(256, 4)
void k_mlp(const unsigned short* __restrict__ ypool,
           const float* __restrict__ w2, const float* __restrict__ b2,
           const float* __restrict__ g2, const float* __restrict__ be2,
           const float* __restrict__ m2, const float* __restrict__ v2,
           const float* __restrict__ w3, const float* __restrict__ b3,
           const float* __restrict__ g3, const float* __restrict__ be3,
           const float* __restrict__ m3, const float* __restrict__ v3,
           float* __restrict__ zbuf)
{
    __shared__ __align__(16) unsigned short As[64 * LDK];   // 13312 B
    __shared__ __align__(16) unsigned short Bs[NP * LDK];   // 23296 B
    __shared__ float s2s[HID], c2s[HID], w3s[HID];          // 1200 B

    const int tid  = threadIdx.x;
    const int u    = blockIdx.x;
    const int b0   = blockIdx.y * 64;
    const int wave = tid >> 6;
    const int lane = tid & 63;
    const int col  = lane & 15;
    const int quad = lane >> 4;

    // ---- stage A: 64 x 96 bf16, 16B chunks (768 total, 3/thread) ----
    {
        const unsigned short* src = ypool + ((size_t)u * BATCH + b0) * KP;
        for (int c = tid; c < 64 * (KP / 8); c += 256) {
            const int m  = c / (KP / 8);
            const int kc = (c % (KP / 8)) * 8;
            *(short8*)(&As[m * LDK + kc]) = *(const short8*)(src + m * KP + kc);
        }
    }
    // ---- stage B: w2 fp32 -> bf16, 100 x 84 real, pads zeroed ----
    {
        const float* src = w2 + (size_t)u * HID * LPOOL;
        for (int c = tid; c < HID * (LPOOL / 4); c += 256) {
            const int n  = c / (LPOOL / 4);
            const int kc = (c % (LPOOL / 4)) * 4;
            const float4 v = *(const float4*)(src + n * LPOOL + kc);
            unsigned short* d = &Bs[n * LDK + kc];
            d[0] = f2bf(v.x); d[1] = f2bf(v.y); d[2] = f2bf(v.z); d[3] = f2bf(v.w);
        }
        for (int c = tid; c < HID * 6; c += 256) {            // k-pad [84,96)
            const int n = c / 6, kc = LPOOL + (c % 6) * 2;
            *(unsigned*)(&Bs[n * LDK + kc]) = 0;
        }
        for (int c = tid; c < (NP - HID) * (KP / 2); c += 256) { // n-pad rows
            const int n = HID + c / (KP / 2), kc = (c % (KP / 2)) * 2;
            *(unsigned*)(&Bs[n * LDK + kc]) = 0;
        }
    }
    if (tid < HID) {
        const int uo = u * HID + tid;
        const float s = g2[uo] * rsqrtf(v2[uo] + EPS);
        s2s[tid] = s;
        c2s[tid] = (b2[uo] - m2[uo]) * s + be2[uo];
        w3s[tid] = w3[uo];
    }
    __syncthreads();

    // ---- A fragments for this wave's M-tile (reused across all N-tiles) ----
    const int mrow = 16 * wave + col;          // A: m = lane&15
    short8 af[3];
#pragma unroll
    for (int s = 0; s < 3; ++s)
        af[s] = *(const short8*)(&As[mrow * LDK + 32 * s + quad * 8]);

    float zp0 = 0.f, zp1 = 0.f, zp2 = 0.f, zp3 = 0.f;
#pragma unroll
    for (int t = 0; t < 7; ++t) {
        float4v acc = {0.f, 0.f, 0.f, 0.f};
        const int nrow = 16 * t + col;         // B: n = lane&15
#pragma unroll
        for (int s = 0; s < 3; ++s) {
            const short8 bfv = *(const short8*)(&Bs[nrow * LDK + 32 * s + quad * 8]);
            acc = __builtin_amdgcn_mfma_f32_16x16x32_bf16(af[s], bfv, acc, 0, 0, 0);
        }
        // D: col = lane&15 (= n index), rows = quad*4 + reg (= m index)
        const bool valid = nrow < HID;
        const float s2  = valid ? s2s[nrow] : 0.f;
        const float c2  = valid ? c2s[nrow] : 0.f;
        const float w3v = valid ? w3s[nrow] : 0.f;
        zp0 = fmaf(fmaxf(fmaf(acc[0], s2, c2), 0.f), w3v, zp0);
        zp1 = fmaf(fmaxf(fmaf(acc[1], s2, c2), 0.f), w3v, zp1);
        zp2 = fmaf(fmaxf(fmaf(acc[2], s2, c2), 0.f), w3v, zp2);
        zp3 = fmaf(fmaxf(fmaf(acc[3], s2, c2), 0.f), w3v, zp3);
    }

    // reduce over the 16 D-columns (lanes sharing quad)
#pragma unroll
    for (int mask = 1; mask < 16; mask <<= 1) {
        zp0 += __shfl_xor(zp0, mask);
        zp1 += __shfl_xor(zp1, mask);
        zp2 += __shfl_xor(zp2, mask);
        zp3 += __shfl_xor(zp3, mask);
    }

    if (col < 4) {
        const float zv = (col == 0) ? zp0 : (col == 1) ? zp1 : (col == 2) ? zp2 : zp3;
        const int m = 16 * wave + quad * 4 + col;
        const float s3 = g3[u] * rsqrtf(v3[u] + EPS);
        const float c3 = (b3[u] - m3[u]) * s3 + be3[u];
        zbuf[(size_t)u * BATCH + b0 + m] = fmaxf(fmaf(zv, s3, c3), 0.f);
    }
}

// ---------------------------------------------------------------------------
// Kernel 3: final linear 300 -> 50.  grid = 50, thread = batch.
// ---------------------------------------------------------------------------
__global__ __launch_bounds__(256, 4)
void k_final(const float* __restrict__ zbuf, const float* __restrict__ wf,
             const float* __restrict__ bf, float* __restrict__ out)
{
    const int n = blockIdx.x;
    const int b = threadIdx.x;
    float a0 = 0.f, a1 = 0.f, a2 = 0.f, a3 = 0.f;
#pragma unroll 5
    for (int u = 0; u < NU; u += 4) {
        a0 = fmaf(zbuf[(size_t)(u + 0) * BATCH + b], wf[n * NU + u + 0], a0);
        a1 = fmaf(zbuf[(size_t)(u + 1) * BATCH + b], wf[n * NU + u + 1], a1);
        a2 = fmaf(zbuf[(size_t)(u + 2) * BATCH + b], wf[n * NU + u + 2], a2);
        a3 = fmaf(zbuf[(size_t)(u + 3) * BATCH + b], wf[n * NU + u + 3], a3);
    }
    out[(size_t)b * NCLS + n] = (a0 + a1) + (a2 + a3) + bf[n];
}

extern "C" void kernel_launch(void* const* d_in, const int* in_sizes, int n_in,
                              void* d_out, int out_size, void* d_ws, size_t ws_size,
                              hipStream_t stream)
{
    const float* x   = (const float*)d_in[0];
    const float* w1  = (const float*)d_in[1];
    const float* b1  = (const float*)d_in[2];
    const float* g1  = (const float*)d_in[3];
    const float* be1 = (const float*)d_in[4];
    const float* m1  = (const float*)d_in[5];
    const float* v1  = (const float*)d_in[6];
    const float* w2  = (const float*)d_in[7];
    const float* b2  = (const float*)d_in[8];
    const float* g2  = (const float*)d_in[9];
    const float* be2 = (const float*)d_in[10];
    const float* m2  = (const float*)d_in[11];
    const float* v2  = (const float*)d_in[12];
    const float* w3  = (const float*)d_in[13];
    const float* b3  = (const float*)d_in[14];
    const float* g3  = (const float*)d_in[15];
    const float* be3 = (const float*)d_in[16];
    const float* m3  = (const float*)d_in[17];
    const float* v3  = (const float*)d_in[18];
    const float* wf  = (const float*)d_in[19];
    const float* bf  = (const float*)d_in[20];

    unsigned short* ypool = (unsigned short*)d_ws;                  // 300*256*96 bf16 = 14.75 MB
    float* zbuf = (float*)(ypool + (size_t)NU * BATCH * KP);        // 300*256 fp32

    dim3 gc(NU / UPB, BATCH);
    k_conv<<<gc, 256, 0, stream>>>(x, w1, b1, g1, be1, m1, v1, ypool);
    dim3 gm(NU, BATCH / 64);
    k_mlp<<<gm, 256, 0, stream>>>(ypool, w2, b2, g2, be2, m2, v2,
                                  w3, b3, g3, be3, m3, v3, zbuf);
    k_final<<<NCLS, 256, 0, stream>>>(zbuf, wf, bf, (float*)d_out);
}

// Round 8
// 212.854 us; speedup vs baseline: 1.6169x; 1.0085x over previous
//
#include <hip/hip_runtime.h>
#include <hip/hip_bf16.h>

#define BATCH    256
#define NU       300
#define LIN      608
#define FILT     19
#define LPOOL    84
#define POOL     7
#define HID      100
#define NCLS     50
#define EPS      1e-5f
#define KP       96    // stage-2 K padded (84 -> 96)
#define NP       112   // stage-2 N padded (100 -> 112)
#define LDK      104   // LDS row stride (shorts) for MFMA tiles
#define WROW     104   // packed-W row stride (shorts)
#define WBROWS   320   // packed-W rows (300 + pad)
#define TCHUNK   112   // t per conv block = lcm(16,7)
#define CROW     116   // conv Cs row stride (floats)
#define UTILE    160   // conv u-tile per grid-z

typedef __attribute__((ext_vector_type(8))) short short8;   // 8 bf16
typedef __attribute__((ext_vector_type(4))) float float4v;  // MFMA acc

__device__ __forceinline__ unsigned short f2bf(float f) {
    unsigned u = __float_as_uint(f);
    u += 0x7fffu + ((u >> 16) & 1u);       // round-to-nearest-even
    return (unsigned short)(u >> 16);
}
__device__ __forceinline__ float bf2f(unsigned short h) {
    return __uint_as_float(((unsigned)h) << 16);
}

// ---------------------------------------------------------------------------
// k_prep: pack w1 -> bf16 hi+lo MFMA-A rows (kk = 32s+8q+jj <-> c=q,
// tap=8s+jj; taps>=19, u>=300 zeroed); split x -> bf16 hi+lo flat.
// ---------------------------------------------------------------------------
__global__ void k_prep(const float* __restrict__ w1, const float* __restrict__ x,
                       unsigned short* __restrict__ Wbh,
                       unsigned short* __restrict__ Wbl,
                       unsigned short* __restrict__ xhi,
                       unsigned short* __restrict__ xlo)
{
    const int idx = blockIdx.x * 256 + threadIdx.x;
    const int NW = WBROWS * WROW;               // 33280
    if (idx < NW) {
        const int u = idx / WROW, kk = idx - u * WROW;
        float wv = 0.f;
        if (u < NU && kk < 96) {
            const int s = kk >> 5, rem = kk & 31, q = rem >> 3, jj = rem & 7;
            const int tap = 8 * s + jj;
            if (tap < FILT) wv = w1[(u * 4 + q) * FILT + tap];
        }
        const unsigned short hi = f2bf(wv);
        Wbh[idx] = hi;
        Wbl[idx] = f2bf(wv - bf2f(hi));
    }
    const int j = idx - NW;
    if (j >= 0 && j < BATCH * 4 * LIN) {
        const float xv = x[j];
        const unsigned short hi = f2bf(xv);
        xhi[j] = hi;
        xlo[j] = f2bf(xv - bf2f(hi));
    }
}

// ---------------------------------------------------------------------------
// k_conv3: conv(4->300,k=19)+bias+BN+exp+maxpool(7), bf16 MFMA implicit GEMM.
//   STRUCTURAL CHANGE vs k_conv2: B tile is an explicit im2col in LDS with
//   LDK-strided rows (exactly the verified k_mlp staging pattern) — the
//   8-shifted-copy trick is gone. W fragments are read directly from global
//   (L2-hot, no W LDS). Numerics: acc = Wh*xh + Wh*xl + Wl*xh (~fp32).
//   Epilogue per M-tile: D -> Cs -> maxpool7 + BN + exp -> bf16 ypool.
// ---------------------------------------------------------------------------
__global__ __launch_bounds__(256, 2)
void k_conv3(const unsigned short* __restrict__ Wbh,
             const unsigned short* __restrict__ Wbl,
             const unsigned short* __restrict__ xhi,
             const unsigned short* __restrict__ xlo,
             const float* __restrict__ b1, const float* __restrict__ g1,
             const float* __restrict__ be1, const float* __restrict__ m1,
             const float* __restrict__ v1,
             unsigned short* __restrict__ ypool)
{
    __shared__ __align__(16) unsigned short Bh[TCHUNK * LDK];  // 23296 B
    __shared__ __align__(16) unsigned short Bl[TCHUNK * LDK];  // 23296 B
    __shared__ float Cs[16 * CROW];                            // 7424 B
    __shared__ float s1s[UTILE], c1s[UTILE];                   // 1280 B

    const int tid   = threadIdx.x;
    const int b     = blockIdx.x;
    const int tc    = blockIdx.y;
    const int ug    = blockIdx.z;
    const int t0    = TCHUNK * tc;
    const int NT    = (tc == 5) ? 2 : 7;       // N-tiles (t) in this block
    const int MTN   = ug ? 9 : 10;             // M-tiles (u)
    const int ubase = ug * UTILE;

    // ---- stage B tile (im2col, hi+lo): Bs[trow][kk] = x[c][t0+trow+tap] ----
    //   kk = 32s+8q+jj <-> c=q, tap=8s+jj  (matches W packing exactly)
    for (int i = tid; i < TCHUNK * 96; i += 256) {   // 42 iters/thread
        const int trow = i / 96;
        const int kk   = i - trow * 96;
        const int s    = kk >> 5, rem = kk & 31;
        const int c    = rem >> 3, jj = rem & 7;
        const int tap  = 8 * s + jj;
        const int tt   = t0 + trow + tap;
        unsigned short vh = 0, vl = 0;
        if (tap < FILT && tt < LIN) {
            const int gi = (b * 4 + c) * LIN + tt;
            vh = xhi[gi];
            vl = xlo[gi];
        }
        Bh[trow * LDK + kk] = vh;
        Bl[trow * LDK + kk] = vl;
    }
    // ---- folded BN consts for this block's u range ----
    if (tid < UTILE) {
        const int u = ubase + tid;
        if (u < NU) {
            const float s = g1[u] * rsqrtf(v1[u] + EPS);
            s1s[tid] = s;
            c1s[tid] = (b1[u] - m1[u]) * s + be1[u];
        } else { s1s[tid] = 0.f; c1s[tid] = 0.f; }
    }
    __syncthreads();

    const int lane = tid & 63;
    const int n    = lane & 15;     // A row (u-within-tile) / B row (t-within-tile)
    const int quad = lane >> 4;     // k-chunk selector
    const int wave = tid >> 6;

    // ---- B fragments (hi & lo): this wave's N-tiles, all K-steps, VGPRs ----
    //   (identical addressing to verified k_mlp: row*LDK + 32s + 8*quad)
    short8 bh[2][3], bl[2][3];
#pragma unroll
    for (int kk2 = 0; kk2 < 2; ++kk2) {
        const int nt = wave + 4 * kk2;
        if (nt < NT) {
#pragma unroll
            for (int s = 0; s < 3; ++s) {
                bh[kk2][s] = *(const short8*)(&Bh[(16 * nt + n) * LDK + 32 * s + 8 * quad]);
                bl[kk2][s] = *(const short8*)(&Bl[(16 * nt + n) * LDK + 32 * s + 8 * quad]);
            }
        }
    }

    const int ep_p = tid & 15;      // epilogue: pool index within chunk
    const int ep_u = tid >> 4;      // epilogue: u-row within M-tile

    for (int mt = 0; mt < MTN; ++mt) {
        // A fragments (W hi & lo) straight from global (L2-hot, 16B-aligned)
        const unsigned short* wrh = Wbh + (size_t)(ubase + mt * 16 + n) * WROW;
        const unsigned short* wrl = Wbl + (size_t)(ubase + mt * 16 + n) * WROW;
        short8 afh[3], afl[3];
#pragma unroll
        for (int s = 0; s < 3; ++s) {
            afh[s] = *(const short8*)(wrh + 32 * s + 8 * quad);
            afl[s] = *(const short8*)(wrl + 32 * s + 8 * quad);
        }

        float4v acc[2];
#pragma unroll
        for (int kk2 = 0; kk2 < 2; ++kk2) {
            acc[kk2] = (float4v){0.f, 0.f, 0.f, 0.f};
            if (wave + 4 * kk2 < NT) {
#pragma unroll
                for (int s = 0; s < 3; ++s)
                    acc[kk2] = __builtin_amdgcn_mfma_f32_16x16x32_bf16(
                        afh[s], bh[kk2][s], acc[kk2], 0, 0, 0);
#pragma unroll
                for (int s = 0; s < 3; ++s)
                    acc[kk2] = __builtin_amdgcn_mfma_f32_16x16x32_bf16(
                        afh[s], bl[kk2][s], acc[kk2], 0, 0, 0);
#pragma unroll
                for (int s = 0; s < 3; ++s)
                    acc[kk2] = __builtin_amdgcn_mfma_f32_16x16x32_bf16(
                        afl[s], bh[kk2][s], acc[kk2], 0, 0, 0);
            }
        }

        __syncthreads();   // Cs free (previous epilogue readers done)
#pragma unroll
        for (int kk2 = 0; kk2 < 2; ++kk2) {
            const int nt = wave + 4 * kk2;
            if (nt < NT) {
#pragma unroll
                for (int r = 0; r < 4; ++r)
                    Cs[(4 * quad + r) * CROW + 16 * nt + n] = acc[kk2][r];
            }
        }
        __syncthreads();

        // epilogue: 256 threads = 16 u-rows x 16 pools
        const int uloc  = mt * 16 + ep_u;
        const int uglob = ubase + uloc;
        if (uglob < NU) {
            const int p = 16 * tc + ep_p;
            unsigned short outv = 0;
            if (p < LPOOL) {
                const float* row = &Cs[ep_u * CROW + 7 * ep_p];
                float mx = row[0];
#pragma unroll
                for (int j = 1; j < 7; ++j) mx = fmaxf(mx, row[j]);
                outv = f2bf(__expf(fmaf(mx, s1s[uloc], c1s[uloc])));
            }
            if (p < KP)
                ypool[((size_t)uglob * BATCH + b) * KP + p] = outv;
        }
    }
}

// ---------------------------------------------------------------------------
// k_mlp: per-unit MLP 84->100 (+BN+ReLU) ->1 (+BN+ReLU), bf16 MFMA.
//   (byte-identical to R3 — verified correct)
// ---------------------------------------------------------------------------
__global__ __launch_bounds__(256, 4)
void k_mlp(const unsigned short* __restrict__ ypool,
           const float* __restrict__ w2, const float* __restrict__ b2,
           const float* __restrict__ g2, const float* __restrict__ be2,
           const float* __restrict__ m2, const float* __restrict__ v2,
           const float* __restrict__ w3, const float* __restrict__ b3,
           const float* __restrict__ g3, const float* __restrict__ be3,
           const float* __restrict__ m3, const float* __restrict__ v3,
           float* __restrict__ zbuf)
{
    __shared__ __align__(16) unsigned short As[64 * LDK];   // 13312 B
    __shared__ __align__(16) unsigned short Bs[NP * LDK];   // 23296 B
    __shared__ float s2s[HID], c2s[HID], w3s[HID];          // 1200 B

    const int tid  = threadIdx.x;
    const int u    = blockIdx.x;
    const int b0   = blockIdx.y * 64;
    const int wave = tid >> 6;
    const int lane = tid & 63;
    const int col  = lane & 15;
    const int quad = lane >> 4;

    {
        const unsigned short* src = ypool + ((size_t)u * BATCH + b0) * KP;
        for (int c = tid; c < 64 * (KP / 8); c += 256) {
            const int m  = c / (KP / 8);
            const int kc = (c % (KP / 8)) * 8;
            *(short8*)(&As[m * LDK + kc]) = *(const short8*)(src + m * KP + kc);
        }
    }
    {
        const float* src = w2 + (size_t)u * HID * LPOOL;
        for (int c = tid; c < HID * (LPOOL / 4); c += 256) {
            const int n  = c / (LPOOL / 4);
            const int kc = (c % (LPOOL / 4)) * 4;
            const float4 v = *(const float4*)(src + n * LPOOL + kc);
            unsigned short* d = &Bs[n * LDK + kc];
            d[0] = f2bf(v.x); d[1] = f2bf(v.y); d[2] = f2bf(v.z); d[3] = f2bf(v.w);
        }
        for (int c = tid; c < HID * 6; c += 256) {            // k-pad [84,96)
            const int n = c / 6, kc = LPOOL + (c % 6) * 2;
            *(unsigned*)(&Bs[n * LDK + kc]) = 0;
        }
        for (int c = tid; c < (NP - HID) * (KP / 2); c += 256) { // n-pad rows
            const int n = HID + c / (KP / 2), kc = (c % (KP / 2)) * 2;
            *(unsigned*)(&Bs[n * LDK + kc]) = 0;
        }
    }
    if (tid < HID) {
        const int uo = u * HID + tid;
        const float s = g2[uo] * rsqrtf(v2[uo] + EPS);
        s2s[tid] = s;
        c2s[tid] = (b2[uo] - m2[uo]) * s + be2[uo];
        w3s[tid] = w3[uo];
    }
    __syncthreads();

    const int mrow = 16 * wave + col;
    short8 af[3];
#pragma unroll
    for (int s = 0; s < 3; ++s)
        af[s] = *(const short8*)(&As[mrow * LDK + 32 * s + quad * 8]);

    float zp0 = 0.f, zp1 = 0.f, zp2 = 0.f, zp3 = 0.f;
#pragma unroll
    for (int t = 0; t < 7; ++t) {
        float4v acc = {0.f, 0.f, 0.f, 0.f};
        const int nrow = 16 * t + col;
#pragma unroll
        for (int s = 0; s < 3; ++s) {
            const short8 bfv = *(const short8*)(&Bs[nrow * LDK + 32 * s + quad * 8]);
            acc = __builtin_amdgcn_mfma_f32_16x16x32_bf16(af[s], bfv, acc, 0, 0, 0);
        }
        const bool valid = nrow < HID;
        const float s2  = valid ? s2s[nrow] : 0.f;
        const float c2  = valid ? c2s[nrow] : 0.f;
        const float w3v = valid ? w3s[nrow] : 0.f;
        zp0 = fmaf(fmaxf(fmaf(acc[0], s2, c2), 0.f), w3v, zp0);
        zp1 = fmaf(fmaxf(fmaf(acc[1], s2, c2), 0.f), w3v, zp1);
        zp2 = fmaf(fmaxf(fmaf(acc[2], s2, c2), 0.f), w3v, zp2);
        zp3 = fmaf(fmaxf(fmaf(acc[3], s2, c2), 0.f), w3v, zp3);
    }

#pragma unroll
    for (int mask = 1; mask < 16; mask <<= 1) {
        zp0 += __shfl_xor(zp0, mask);
        zp1 += __shfl_xor(zp1, mask);
        zp2 += __shfl_xor(zp2, mask);
        zp3 += __shfl_xor(zp3, mask);
    }

    if (col < 4) {
        const float zv = (col == 0) ? zp0 : (col == 1) ? zp1 : (col == 2) ? zp2 : zp3;
        const int m = 16 * wave + quad * 4 + col;
        const float s3 = g3[u] * rsqrtf(v3[u] + EPS);
        const float c3 = (b3[u] - m3[u]) * s3 + be3[u];
        zbuf[(size_t)u * BATCH + b0 + m] = fmaxf(fmaf(zv, s3, c3), 0.f);
    }
}

// ---------------------------------------------------------------------------
// k_final: 300 -> 50.  (byte-identical to R3 — verified correct)
// ---------------------------------------------------------------------------
__global__ __launch_bounds__(256, 4)
void k_final(const float* __restrict__ zbuf, const float* __restrict__ wf,
             const float* __restrict__ bf, float* __restrict__ out)
{
    const int n = blockIdx.x;
    const int b = threadIdx.x;
    float a0 = 0.f, a1 = 0.f, a2 = 0.f, a3 = 0.f;
#pragma unroll 5
    for (int u = 0; u < NU; u += 4) {
        a0 = fmaf(zbuf[(size_t)(u + 0) * BATCH + b], wf[n * NU + u + 0], a0);
        a1 = fmaf(zbuf[(size_t)(u + 1) * BATCH + b], wf[n * NU + u + 1], a1);
        a2 = fmaf(zbuf[(size_t)(u + 2) * BATCH + b], wf[n * NU + u + 2], a2);
        a3 = fmaf(zbuf[(size_t)(u + 3) * BATCH + b], wf[n * NU + u + 3], a3);
    }
    out[(size_t)b * NCLS + n] = (a0 + a1) + (a2 + a3) + bf[n];
}

extern "C" void kernel_launch(void* const* d_in, const int* in_sizes, int n_in,
                              void* d_out, int out_size, void* d_ws, size_t ws_size,
                              hipStream_t stream)
{
    const float* x   = (const float*)d_in[0];
    const float* w1  = (const float*)d_in[1];
    const float* b1  = (const float*)d_in[2];
    const float* g1  = (const float*)d_in[3];
    const float* be1 = (const float*)d_in[4];
    const float* m1  = (const float*)d_in[5];
    const float* v1  = (const float*)d_in[6];
    const float* w2  = (const float*)d_in[7];
    const float* b2  = (const float*)d_in[8];
    const float* g2  = (const float*)d_in[9];
    const float* be2 = (const float*)d_in[10];
    const float* m2  = (const float*)d_in[11];
    const float* v2  = (const float*)d_in[12];
    const float* w3  = (const float*)d_in[13];
    const float* b3  = (const float*)d_in[14];
    const float* g3  = (const float*)d_in[15];
    const float* be3 = (const float*)d_in[16];
    const float* m3  = (const float*)d_in[17];
    const float* v3  = (const float*)d_in[18];
    const float* wf  = (const float*)d_in[19];
    const float* bf  = (const float*)d_in[20];

    // workspace layout (bytes):
    //   ypool  bf16 [300][256][96]  @ 0          (14,745,600)
    //   zbuf   f32  [300][256]      @ 14,745,600 (307,200)
    //   Wbh    bf16 [320][104]      @ 15,052,800 (66,560)
    //   Wbl    bf16 [320][104]      @ 15,119,360 (66,560)
    //   xhi    bf16 [256][4][608]   @ 15,185,920 (1,245,184)
    //   xlo    bf16 [256][4][608]   @ 16,431,104 (1,245,184)
    unsigned short* ypool = (unsigned short*)d_ws;
    float* zbuf = (float*)((char*)d_ws + 14745600);
    unsigned short* Wbh = (unsigned short*)((char*)d_ws + 15052800);
    unsigned short* Wbl = (unsigned short*)((char*)d_ws + 15119360);
    unsigned short* xhi = (unsigned short*)((char*)d_ws + 15185920);
    unsigned short* xlo = (unsigned short*)((char*)d_ws + 16431104);

    const int prep_elems = WBROWS * WROW + BATCH * 4 * LIN;
    k_prep<<<(prep_elems + 255) / 256, 256, 0, stream>>>(w1, x, Wbh, Wbl, xhi, xlo);

    dim3 gc(BATCH, 6, 2);
    k_conv3<<<gc, 256, 0, stream>>>(Wbh, Wbl, xhi, xlo, b1, g1, be1, m1, v1, ypool);

    dim3 gm(NU, BATCH / 64);
    k_mlp<<<gm, 256, 0, stream>>>(ypool, w2, b2, g2, be2, m2, v2,
                                  w3, b3, g3, be3, m3, v3, zbuf);

    k_final<<<NCLS, 256, 0, stream>>>(zbuf, wf, bf, (float*)d_out);
}

// Round 9
// 207.426 us; speedup vs baseline: 1.6592x; 1.0262x over previous
//
#include <hip/hip_runtime.h>
#include <hip/hip_bf16.h>

#define BATCH    256
#define NU       300
#define LIN      608
#define FILT     19
#define LPOOL    84
#define POOL     7
#define HID      100
#define NCLS     50
#define EPS      1e-5f
#define KP       96    // stage-2 K padded (84 -> 96)
#define NP       112   // stage-2 N padded (100 -> 112)
#define LDK      104   // LDS row stride (shorts) for MFMA tiles
#define WROW     104   // packed-W row stride (shorts)
#define WBROWS   320   // packed-W rows (300 + pad)
#define TCHUNK   112   // t per conv block = lcm(16,7)
#define CROW     116   // conv Cs row stride (floats)
#define UTILE    160   // conv u-tile per grid-z
#define BH       128   // batches per k_mlp block

typedef __attribute__((ext_vector_type(8))) short short8;   // 8 bf16
typedef __attribute__((ext_vector_type(4))) float float4v;  // MFMA acc

__device__ __forceinline__ unsigned short f2bf(float f) {
    unsigned u = __float_as_uint(f);
    u += 0x7fffu + ((u >> 16) & 1u);       // round-to-nearest-even
    return (unsigned short)(u >> 16);
}
__device__ __forceinline__ float bf2f(unsigned short h) {
    return __uint_as_float(((unsigned)h) << 16);
}

// ---------------------------------------------------------------------------
// k_prep: (byte-identical to R8 — verified)
// ---------------------------------------------------------------------------
__global__ void k_prep(const float* __restrict__ w1, const float* __restrict__ x,
                       unsigned short* __restrict__ Wbh,
                       unsigned short* __restrict__ Wbl,
                       unsigned short* __restrict__ xhi,
                       unsigned short* __restrict__ xlo)
{
    const int idx = blockIdx.x * 256 + threadIdx.x;
    const int NW = WBROWS * WROW;               // 33280
    if (idx < NW) {
        const int u = idx / WROW, kk = idx - u * WROW;
        float wv = 0.f;
        if (u < NU && kk < 96) {
            const int s = kk >> 5, rem = kk & 31, q = rem >> 3, jj = rem & 7;
            const int tap = 8 * s + jj;
            if (tap < FILT) wv = w1[(u * 4 + q) * FILT + tap];
        }
        const unsigned short hi = f2bf(wv);
        Wbh[idx] = hi;
        Wbl[idx] = f2bf(wv - bf2f(hi));
    }
    const int j = idx - NW;
    if (j >= 0 && j < BATCH * 4 * LIN) {
        const float xv = x[j];
        const unsigned short hi = f2bf(xv);
        xhi[j] = hi;
        xlo[j] = f2bf(xv - bf2f(hi));
    }
}

// ---------------------------------------------------------------------------
// k_conv3: (byte-identical to R8 — verified, 92.6 us measured)
// ---------------------------------------------------------------------------
__global__ __launch_bounds__(256, 2)
void k_conv3(const unsigned short* __restrict__ Wbh,
             const unsigned short* __restrict__ Wbl,
             const unsigned short* __restrict__ xhi,
             const unsigned short* __restrict__ xlo,
             const float* __restrict__ b1, const float* __restrict__ g1,
             const float* __restrict__ be1, const float* __restrict__ m1,
             const float* __restrict__ v1,
             unsigned short* __restrict__ ypool)
{
    __shared__ __align__(16) unsigned short Bh[TCHUNK * LDK];  // 23296 B
    __shared__ __align__(16) unsigned short Bl[TCHUNK * LDK];  // 23296 B
    __shared__ float Cs[16 * CROW];                            // 7424 B
    __shared__ float s1s[UTILE], c1s[UTILE];                   // 1280 B

    const int tid   = threadIdx.x;
    const int b     = blockIdx.x;
    const int tc    = blockIdx.y;
    const int ug    = blockIdx.z;
    const int t0    = TCHUNK * tc;
    const int NT    = (tc == 5) ? 2 : 7;       // N-tiles (t) in this block
    const int MTN   = ug ? 9 : 10;             // M-tiles (u)
    const int ubase = ug * UTILE;

    for (int i = tid; i < TCHUNK * 96; i += 256) {
        const int trow = i / 96;
        const int kk   = i - trow * 96;
        const int s    = kk >> 5, rem = kk & 31;
        const int c    = rem >> 3, jj = rem & 7;
        const int tap  = 8 * s + jj;
        const int tt   = t0 + trow + tap;
        unsigned short vh = 0, vl = 0;
        if (tap < FILT && tt < LIN) {
            const int gi = (b * 4 + c) * LIN + tt;
            vh = xhi[gi];
            vl = xlo[gi];
        }
        Bh[trow * LDK + kk] = vh;
        Bl[trow * LDK + kk] = vl;
    }
    if (tid < UTILE) {
        const int u = ubase + tid;
        if (u < NU) {
            const float s = g1[u] * rsqrtf(v1[u] + EPS);
            s1s[tid] = s;
            c1s[tid] = (b1[u] - m1[u]) * s + be1[u];
        } else { s1s[tid] = 0.f; c1s[tid] = 0.f; }
    }
    __syncthreads();

    const int lane = tid & 63;
    const int n    = lane & 15;
    const int quad = lane >> 4;
    const int wave = tid >> 6;

    short8 bh[2][3], bl[2][3];
#pragma unroll
    for (int kk2 = 0; kk2 < 2; ++kk2) {
        const int nt = wave + 4 * kk2;
        if (nt < NT) {
#pragma unroll
            for (int s = 0; s < 3; ++s) {
                bh[kk2][s] = *(const short8*)(&Bh[(16 * nt + n) * LDK + 32 * s + 8 * quad]);
                bl[kk2][s] = *(const short8*)(&Bl[(16 * nt + n) * LDK + 32 * s + 8 * quad]);
            }
        }
    }

    const int ep_p = tid & 15;
    const int ep_u = tid >> 4;

    for (int mt = 0; mt < MTN; ++mt) {
        const unsigned short* wrh = Wbh + (size_t)(ubase + mt * 16 + n) * WROW;
        const unsigned short* wrl = Wbl + (size_t)(ubase + mt * 16 + n) * WROW;
        short8 afh[3], afl[3];
#pragma unroll
        for (int s = 0; s < 3; ++s) {
            afh[s] = *(const short8*)(wrh + 32 * s + 8 * quad);
            afl[s] = *(const short8*)(wrl + 32 * s + 8 * quad);
        }

        float4v acc[2];
#pragma unroll
        for (int kk2 = 0; kk2 < 2; ++kk2) {
            acc[kk2] = (float4v){0.f, 0.f, 0.f, 0.f};
            if (wave + 4 * kk2 < NT) {
#pragma unroll
                for (int s = 0; s < 3; ++s)
                    acc[kk2] = __builtin_amdgcn_mfma_f32_16x16x32_bf16(
                        afh[s], bh[kk2][s], acc[kk2], 0, 0, 0);
#pragma unroll
                for (int s = 0; s < 3; ++s)
                    acc[kk2] = __builtin_amdgcn_mfma_f32_16x16x32_bf16(
                        afh[s], bl[kk2][s], acc[kk2], 0, 0, 0);
#pragma unroll
                for (int s = 0; s < 3; ++s)
                    acc[kk2] = __builtin_amdgcn_mfma_f32_16x16x32_bf16(
                        afl[s], bh[kk2][s], acc[kk2], 0, 0, 0);
            }
        }

        __syncthreads();
#pragma unroll
        for (int kk2 = 0; kk2 < 2; ++kk2) {
            const int nt = wave + 4 * kk2;
            if (nt < NT) {
#pragma unroll
                for (int r = 0; r < 4; ++r)
                    Cs[(4 * quad + r) * CROW + 16 * nt + n] = acc[kk2][r];
            }
        }
        __syncthreads();

        const int uloc  = mt * 16 + ep_u;
        const int uglob = ubase + uloc;
        if (uglob < NU) {
            const int p = 16 * tc + ep_p;
            unsigned short outv = 0;
            if (p < LPOOL) {
                const float* row = &Cs[ep_u * CROW + 7 * ep_p];
                float mx = row[0];
#pragma unroll
                for (int j = 1; j < 7; ++j) mx = fmaxf(mx, row[j]);
                outv = f2bf(__expf(fmaf(mx, s1s[uloc], c1s[uloc])));
            }
            if (p < KP)
                ypool[((size_t)uglob * BATCH + b) * KP + p] = outv;
        }
    }
}

// ---------------------------------------------------------------------------
// k_mlp v3: per-unit MLP 84->100 (+BN+ReLU) ->1 (+BN+ReLU), bf16 MFMA,
//   TRANSPOSED orientation: A = w2 (m=o), B = y (n=batch), D[row=o][col=b].
//   grid (300 u, 2 b-halves), 4 waves; wave owns 2 b-tiles (32 batches),
//   loops 7 o-tiles x 3 K-steps. Epilogue: packed (s2,c2,w3) float4 per o
//   (LDS broadcast), per-lane partial z over o-rows, 2-step shfl_xor reduce
//   over quads, fused BN3+ReLU -> zbuf[u][b].
//   51.7 KB LDS -> 3 blocks/CU; 600 blocks = one residency round.
// ---------------------------------------------------------------------------
__global__ __launch_bounds__(256, 3)
void k_mlp(const unsigned short* __restrict__ ypool,
           const float* __restrict__ w2, const float* __restrict__ b2,
           const float* __restrict__ g2, const float* __restrict__ be2,
           const float* __restrict__ m2, const float* __restrict__ v2,
           const float* __restrict__ w3, const float* __restrict__ b3,
           const float* __restrict__ g3, const float* __restrict__ be3,
           const float* __restrict__ m3, const float* __restrict__ v3,
           float* __restrict__ zbuf)
{
    __shared__ __align__(16) unsigned short As[NP * LDK];   // w2 tile 23296 B
    __shared__ __align__(16) unsigned short Bs[BH * LDK];   // y  tile 26624 B
    __shared__ __align__(16) float4 cs4[NP];                // (s2,c2,w3,0) 1792 B

    const int tid = threadIdx.x;
    const int u   = blockIdx.x;
    const int b0  = blockIdx.y * BH;

    // ---- stage As: w2[u] fp32 -> bf16, o-major rows, kk-pad zeroed ----
    {
        const float* src = w2 + (size_t)u * HID * LPOOL;
        for (int c = tid; c < HID * (LPOOL / 4); c += 256) {
            const int o  = c / (LPOOL / 4);
            const int kc = (c % (LPOOL / 4)) * 4;
            const float4 v = *(const float4*)(src + o * LPOOL + kc);
            unsigned short* d = &As[o * LDK + kc];
            d[0] = f2bf(v.x); d[1] = f2bf(v.y); d[2] = f2bf(v.z); d[3] = f2bf(v.w);
        }
        for (int c = tid; c < HID * 6; c += 256) {            // k-pad [84,96)
            const int o = c / 6, kc = LPOOL + (c % 6) * 2;
            *(unsigned*)(&As[o * LDK + kc]) = 0;
        }
        for (int c = tid; c < (NP - HID) * (KP / 2); c += 256) { // o-pad rows
            const int o = HID + c / (KP / 2), kc = (c % (KP / 2)) * 2;
            *(unsigned*)(&As[o * LDK + kc]) = 0;
        }
    }
    // ---- stage Bs: ypool[u][b0..b0+BH) rows (16B chunks) ----
    {
        const unsigned short* ys = ypool + ((size_t)u * BATCH + b0) * KP;
        for (int c = tid; c < BH * (KP / 8); c += 256) {
            const int n  = c / (KP / 8);
            const int kc = (c % (KP / 8)) * 8;
            *(short8*)(&Bs[n * LDK + kc]) = *(const short8*)(ys + n * KP + kc);
        }
    }
    // ---- stage packed BN2/w3 consts ----
    if (tid < NP) {
        float4 cv = {0.f, 0.f, 0.f, 0.f};
        if (tid < HID) {
            const int uo = u * HID + tid;
            const float s = g2[uo] * rsqrtf(v2[uo] + EPS);
            cv.x = s;
            cv.y = (b2[uo] - m2[uo]) * s + be2[uo];
            cv.z = w3[uo];
        }
        cs4[tid] = cv;
    }
    __syncthreads();

    const int lane = tid & 63;
    const int wave = tid >> 6;
    const int col  = lane & 15;
    const int quad = lane >> 4;

    // ---- B fragments: wave owns nt = 2*wave, 2*wave+1 ----
    short8 bf_[2][3];
#pragma unroll
    for (int j = 0; j < 2; ++j) {
        const int brow = 16 * (2 * wave + j) + col;
#pragma unroll
        for (int s = 0; s < 3; ++s)
            bf_[j][s] = *(const short8*)(&Bs[brow * LDK + 32 * s + 8 * quad]);
    }

    float zp0 = 0.f, zp1 = 0.f;
#pragma unroll
    for (int mt = 0; mt < 7; ++mt) {
        short8 af[3];
#pragma unroll
        for (int s = 0; s < 3; ++s)
            af[s] = *(const short8*)(&As[(16 * mt + col) * LDK + 32 * s + 8 * quad]);

        float4v a0 = {0.f, 0.f, 0.f, 0.f}, a1 = {0.f, 0.f, 0.f, 0.f};
#pragma unroll
        for (int s = 0; s < 3; ++s) {
            a0 = __builtin_amdgcn_mfma_f32_16x16x32_bf16(af[s], bf_[0][s], a0, 0, 0, 0);
            a1 = __builtin_amdgcn_mfma_f32_16x16x32_bf16(af[s], bf_[1][s], a1, 0, 0, 0);
        }
        // D: row (o) = 16*mt + quad*4 + r, col (b) = lane&15
#pragma unroll
        for (int r = 0; r < 4; ++r) {
            const float4 cv = cs4[16 * mt + 4 * quad + r];
            zp0 = fmaf(fmaxf(fmaf(a0[r], cv.x, cv.y), 0.f), cv.z, zp0);
            zp1 = fmaf(fmaxf(fmaf(a1[r], cv.x, cv.y), 0.f), cv.z, zp1);
        }
    }

    // reduce over quads (lane bits 4,5)
    zp0 += __shfl_xor(zp0, 16); zp0 += __shfl_xor(zp0, 32);
    zp1 += __shfl_xor(zp1, 16); zp1 += __shfl_xor(zp1, 32);

    if (quad == 0) {
        const float s3 = g3[u] * rsqrtf(v3[u] + EPS);
        const float c3 = (b3[u] - m3[u]) * s3 + be3[u];
        const int bA = b0 + 16 * (2 * wave + 0) + col;
        const int bB = b0 + 16 * (2 * wave + 1) + col;
        zbuf[(size_t)u * BATCH + bA] = fmaxf(fmaf(zp0, s3, c3), 0.f);
        zbuf[(size_t)u * BATCH + bB] = fmaxf(fmaf(zp1, s3, c3), 0.f);
    }
}

// ---------------------------------------------------------------------------
// k_final: 300 -> 50.  (byte-identical to R3/R8 — verified correct)
// ---------------------------------------------------------------------------
__global__ __launch_bounds__(256, 4)
void k_final(const float* __restrict__ zbuf, const float* __restrict__ wf,
             const float* __restrict__ bf, float* __restrict__ out)
{
    const int n = blockIdx.x;
    const int b = threadIdx.x;
    float a0 = 0.f, a1 = 0.f, a2 = 0.f, a3 = 0.f;
#pragma unroll 5
    for (int u = 0; u < NU; u += 4) {
        a0 = fmaf(zbuf[(size_t)(u + 0) * BATCH + b], wf[n * NU + u + 0], a0);
        a1 = fmaf(zbuf[(size_t)(u + 1) * BATCH + b], wf[n * NU + u + 1], a1);
        a2 = fmaf(zbuf[(size_t)(u + 2) * BATCH + b], wf[n * NU + u + 2], a2);
        a3 = fmaf(zbuf[(size_t)(u + 3) * BATCH + b], wf[n * NU + u + 3], a3);
    }
    out[(size_t)b * NCLS + n] = (a0 + a1) + (a2 + a3) + bf[n];
}

extern "C" void kernel_launch(void* const* d_in, const int* in_sizes, int n_in,
                              void* d_out, int out_size, void* d_ws, size_t ws_size,
                              hipStream_t stream)
{
    const float* x   = (const float*)d_in[0];
    const float* w1  = (const float*)d_in[1];
    const float* b1  = (const float*)d_in[2];
    const float* g1  = (const float*)d_in[3];
    const float* be1 = (const float*)d_in[4];
    const float* m1  = (const float*)d_in[5];
    const float* v1  = (const float*)d_in[6];
    const float* w2  = (const float*)d_in[7];
    const float* b2  = (const float*)d_in[8];
    const float* g2  = (const float*)d_in[9];
    const float* be2 = (const float*)d_in[10];
    const float* m2  = (const float*)d_in[11];
    const float* v2  = (const float*)d_in[12];
    const float* w3  = (const float*)d_in[13];
    const float* b3  = (const float*)d_in[14];
    const float* g3  = (const float*)d_in[15];
    const float* be3 = (const float*)d_in[16];
    const float* m3  = (const float*)d_in[17];
    const float* v3  = (const float*)d_in[18];
    const float* wf  = (const float*)d_in[19];
    const float* bf  = (const float*)d_in[20];

    // workspace layout (bytes):
    //   ypool  bf16 [300][256][96]  @ 0          (14,745,600)
    //   zbuf   f32  [300][256]      @ 14,745,600 (307,200)
    //   Wbh    bf16 [320][104]      @ 15,052,800 (66,560)
    //   Wbl    bf16 [320][104]      @ 15,119,360 (66,560)
    //   xhi    bf16 [256][4][608]   @ 15,185,920 (1,245,184)
    //   xlo    bf16 [256][4][608]   @ 16,431,104 (1,245,184)
    unsigned short* ypool = (unsigned short*)d_ws;
    float* zbuf = (float*)((char*)d_ws + 14745600);
    unsigned short* Wbh = (unsigned short*)((char*)d_ws + 15052800);
    unsigned short* Wbl = (unsigned short*)((char*)d_ws + 15119360);
    unsigned short* xhi = (unsigned short*)((char*)d_ws + 15185920);
    unsigned short* xlo = (unsigned short*)((char*)d_ws + 16431104);

    const int prep_elems = WBROWS * WROW + BATCH * 4 * LIN;
    k_prep<<<(prep_elems + 255) / 256, 256, 0, stream>>>(w1, x, Wbh, Wbl, xhi, xlo);

    dim3 gc(BATCH, 6, 2);
    k_conv3<<<gc, 256, 0, stream>>>(Wbh, Wbl, xhi, xlo, b1, g1, be1, m1, v1, ypool);

    dim3 gm(NU, BATCH / BH);
    k_mlp<<<gm, 256, 0, stream>>>(ypool, w2, b2, g2, be2, m2, v2,
                                  w3, b3, g3, be3, m3, v3, zbuf);

    k_final<<<NCLS, 256, 0, stream>>>(zbuf, wf, bf, (float*)d_out);
}

// Round 10
// 180.469 us; speedup vs baseline: 1.9071x; 1.1494x over previous
//
#include <hip/hip_runtime.h>
#include <hip/hip_bf16.h>

#define BATCH    256
#define NU       300
#define LIN      608
#define FILT     19
#define LPOOL    84
#define POOL     7
#define HID      100
#define NCLS     50
#define EPS      1e-5f
#define KP       96    // stage-2 K padded (84 -> 96)
#define NP       112   // stage-2 N padded (100 -> 112)
#define LDK      104   // LDS row stride (shorts) for MFMA tiles
#define WROW     104   // packed-W row stride (shorts)
#define WBROWS   320   // packed-W rows (300 + pad)
#define TCHUNK   112   // t per conv block = lcm(16,7)
#define CROW     116   // conv Cs row stride (floats)
#define MTN      19    // conv u-tiles (rows 0..303 cover u<300)
#define BH       128   // batches per k_mlp block

typedef __attribute__((ext_vector_type(8))) short short8;   // 8 bf16
typedef __attribute__((ext_vector_type(4))) float float4v;  // MFMA acc

__device__ __forceinline__ unsigned short f2bf(float f) {
    unsigned u = __float_as_uint(f);
    u += 0x7fffu + ((u >> 16) & 1u);       // round-to-nearest-even
    return (unsigned short)(u >> 16);
}
__device__ __forceinline__ float bf2f(unsigned short h) {
    return __uint_as_float(((unsigned)h) << 16);
}

// ---------------------------------------------------------------------------
// k_prep: pack w1 -> bf16 hi+lo MFMA-A rows with kk = 24*c + tap (taps>=19,
// u>=300 zeroed); split x -> hi/lo bf16 packed in one uint (hi low16, lo
// high16) so conv staging loads are 4B-aligned vectors.
// ---------------------------------------------------------------------------
__global__ void k_prep(const float* __restrict__ w1, const float* __restrict__ x,
                       unsigned short* __restrict__ Wbh,
                       unsigned short* __restrict__ Wbl,
                       unsigned int* __restrict__ xc)
{
    const int idx = blockIdx.x * 256 + threadIdx.x;
    const int NW = WBROWS * WROW;               // 33280
    if (idx < NW) {
        const int u = idx / WROW, kk = idx - u * WROW;
        float wv = 0.f;
        if (u < NU && kk < 96) {
            const int c = kk / 24, tap = kk - 24 * c;
            if (tap < FILT) wv = w1[(u * 4 + c) * FILT + tap];
        }
        const unsigned short hi = f2bf(wv);
        Wbh[idx] = hi;
        Wbl[idx] = f2bf(wv - bf2f(hi));
    }
    const int j = idx - NW;
    if (j >= 0 && j < BATCH * 4 * LIN) {
        const float xv = x[j];
        const unsigned short hi = f2bf(xv);
        const unsigned short lo = f2bf(xv - bf2f(hi));
        xc[j] = (unsigned)hi | ((unsigned)lo << 16);
    }
}

// ---------------------------------------------------------------------------
// k_conv4: conv(4->300,k=19)+bias+BN+exp+maxpool(7), bf16 MFMA implicit GEMM,
//   split numerics acc = Wh*xh + Wh*xl + Wl*xh (~fp32).
//   vs k_conv3: (1) kk = 24c+tap -> im2col 8-tap groups are contiguous x
//   spans: staged as 2x dwordx4 loads (4B-aligned via hi/lo-interleaved xc)
//   + unpack + 2x ds_write_b128 (8x less staging work); (2) no ug split —
//   one block does all 19 u-tiles (half the blocks, half the staging);
//   (3) double-buffered Cs -> 1 barrier per u-tile, epilogue overlaps the
//   next tile's MFMAs. LDS 63.9 KB, 2 blocks/CU.
// ---------------------------------------------------------------------------
__global__ __launch_bounds__(256, 2)
void k_conv4(const unsigned short* __restrict__ Wbh,
             const unsigned short* __restrict__ Wbl,
             const unsigned int* __restrict__ xc,
             const float* __restrict__ b1, const float* __restrict__ g1,
             const float* __restrict__ be1, const float* __restrict__ m1,
             const float* __restrict__ v1,
             unsigned short* __restrict__ ypool)
{
    __shared__ __align__(16) unsigned short Bh[TCHUNK * LDK];  // 23296 B
    __shared__ __align__(16) unsigned short Bl[TCHUNK * LDK];  // 23296 B
    __shared__ float Cs[2][16 * CROW];                         // 14848 B
    __shared__ float s1s[MTN * 16], c1s[MTN * 16];             // 2432 B

    const int tid = threadIdx.x;
    const int b   = blockIdx.x;
    const int tc  = blockIdx.y;
    const int t0  = TCHUNK * tc;
    const int NT  = (tc == 5) ? 2 : 7;         // N-tiles (t) in this block

    // ---- stage B tile (im2col hi+lo): row trow, kk = 24c + 8*third + j ----
    for (int i = tid; i < TCHUNK * 12; i += 256) {
        const int trow = i / 12;
        if (trow >= 16 * NT) continue;         // unused rows (tc==5)
        const int rem   = i - 12 * trow;
        const int c     = rem / 3;
        const int third = rem - 3 * c;
        const int kkb   = 24 * c + 8 * third;
        const int tt0   = t0 + trow + 8 * third;
        const unsigned int* src = xc + ((b * 4 + c) * LIN + tt0);

        unsigned int w[8];
        if (third < 2 && tt0 + 8 <= LIN) {     // all 8 taps valid & in range
            const uint4 v0 = *(const uint4*)(src);
            const uint4 v1 = *(const uint4*)(src + 4);
            w[0] = v0.x; w[1] = v0.y; w[2] = v0.z; w[3] = v0.w;
            w[4] = v1.x; w[5] = v1.y; w[6] = v1.z; w[7] = v1.w;
        } else {
#pragma unroll
            for (int j = 0; j < 8; ++j) {
                const int tap = 8 * third + j;
                const int tt  = tt0 + j;
                unsigned int v = 0;
                if (tap < FILT && tt < LIN) v = src[j];
                w[j] = v;
            }
        }
        short8 hv, lv;
#pragma unroll
        for (int j = 0; j < 8; ++j) {
            hv[j] = (short)(w[j] & 0xffffu);
            lv[j] = (short)(w[j] >> 16);
        }
        *(short8*)(&Bh[trow * LDK + kkb]) = hv;
        *(short8*)(&Bl[trow * LDK + kkb]) = lv;
    }
    // ---- folded BN consts ----
    for (int i = tid; i < MTN * 16; i += 256) {
        if (i < NU) {
            const float s = g1[i] * rsqrtf(v1[i] + EPS);
            s1s[i] = s;
            c1s[i] = (b1[i] - m1[i]) * s + be1[i];
        } else { s1s[i] = 0.f; c1s[i] = 0.f; }
    }
    __syncthreads();

    const int lane = tid & 63;
    const int n    = lane & 15;
    const int quad = lane >> 4;
    const int wave = tid >> 6;

    // ---- B fragments (hi & lo): wave's N-tiles, all K-steps, in VGPRs ----
    short8 bh[2][3], bl[2][3];
#pragma unroll
    for (int kk2 = 0; kk2 < 2; ++kk2) {
        const int nt = wave + 4 * kk2;
        if (nt < NT) {
#pragma unroll
            for (int s = 0; s < 3; ++s) {
                bh[kk2][s] = *(const short8*)(&Bh[(16 * nt + n) * LDK + 32 * s + 8 * quad]);
                bl[kk2][s] = *(const short8*)(&Bl[(16 * nt + n) * LDK + 32 * s + 8 * quad]);
            }
        }
    }

    const int ep_p = tid & 15;      // epilogue: pool index within chunk
    const int ep_u = tid >> 4;      // epilogue: u-row within M-tile

    for (int mt = 0; mt < MTN; ++mt) {
        // A fragments (W hi & lo) straight from global (L2-hot)
        const unsigned short* wrh = Wbh + (size_t)(mt * 16 + n) * WROW;
        const unsigned short* wrl = Wbl + (size_t)(mt * 16 + n) * WROW;
        short8 afh[3], afl[3];
#pragma unroll
        for (int s = 0; s < 3; ++s) {
            afh[s] = *(const short8*)(wrh + 32 * s + 8 * quad);
            afl[s] = *(const short8*)(wrl + 32 * s + 8 * quad);
        }

        float4v acc[2];
#pragma unroll
        for (int kk2 = 0; kk2 < 2; ++kk2) {
            acc[kk2] = (float4v){0.f, 0.f, 0.f, 0.f};
            if (wave + 4 * kk2 < NT) {
#pragma unroll
                for (int s = 0; s < 3; ++s)
                    acc[kk2] = __builtin_amdgcn_mfma_f32_16x16x32_bf16(
                        afh[s], bh[kk2][s], acc[kk2], 0, 0, 0);
#pragma unroll
                for (int s = 0; s < 3; ++s)
                    acc[kk2] = __builtin_amdgcn_mfma_f32_16x16x32_bf16(
                        afh[s], bl[kk2][s], acc[kk2], 0, 0, 0);
#pragma unroll
                for (int s = 0; s < 3; ++s)
                    acc[kk2] = __builtin_amdgcn_mfma_f32_16x16x32_bf16(
                        afl[s], bh[kk2][s], acc[kk2], 0, 0, 0);
            }
        }

        // D -> Cs[mt&1]; single barrier (dbuf: epilogue overlaps next tile)
        float* cbuf = Cs[mt & 1];
#pragma unroll
        for (int kk2 = 0; kk2 < 2; ++kk2) {
            const int nt = wave + 4 * kk2;
            if (nt < NT) {
#pragma unroll
                for (int r = 0; r < 4; ++r)
                    cbuf[(4 * quad + r) * CROW + 16 * nt + n] = acc[kk2][r];
            }
        }
        __syncthreads();

        // epilogue: 256 threads = 16 u-rows x 16 pools
        const int uglob = mt * 16 + ep_u;
        if (uglob < NU) {
            const int p = 16 * tc + ep_p;
            unsigned short outv = 0;
            if (p < LPOOL) {
                const float* row = &cbuf[ep_u * CROW + 7 * ep_p];
                float mx = row[0];
#pragma unroll
                for (int j = 1; j < 7; ++j) mx = fmaxf(mx, row[j]);
                outv = f2bf(__expf(fmaf(mx, s1s[uglob], c1s[uglob])));
            }
            if (p < KP)
                ypool[((size_t)uglob * BATCH + b) * KP + p] = outv;
        }
    }
}

// ---------------------------------------------------------------------------
// k_mlp v3: (byte-identical to R9 — verified, pass)
// ---------------------------------------------------------------------------
__global__ __launch_bounds__(256, 3)
void k_mlp(const unsigned short* __restrict__ ypool,
           const float* __restrict__ w2, const float* __restrict__ b2,
           const float* __restrict__ g2, const float* __restrict__ be2,
           const float* __restrict__ m2, const float* __restrict__ v2,
           const float* __restrict__ w3, const float* __restrict__ b3,
           const float* __restrict__ g3, const float* __restrict__ be3,
           const float* __restrict__ m3, const float* __restrict__ v3,
           float* __restrict__ zbuf)
{
    __shared__ __align__(16) unsigned short As[NP * LDK];   // w2 tile 23296 B
    __shared__ __align__(16) unsigned short Bs[BH * LDK];   // y  tile 26624 B
    __shared__ __align__(16) float4 cs4[NP];                // (s2,c2,w3,0)

    const int tid = threadIdx.x;
    const int u   = blockIdx.x;
    const int b0  = blockIdx.y * BH;

    {
        const float* src = w2 + (size_t)u * HID * LPOOL;
        for (int c = tid; c < HID * (LPOOL / 4); c += 256) {
            const int o  = c / (LPOOL / 4);
            const int kc = (c % (LPOOL / 4)) * 4;
            const float4 v = *(const float4*)(src + o * LPOOL + kc);
            unsigned short* d = &As[o * LDK + kc];
            d[0] = f2bf(v.x); d[1] = f2bf(v.y); d[2] = f2bf(v.z); d[3] = f2bf(v.w);
        }
        for (int c = tid; c < HID * 6; c += 256) {            // k-pad [84,96)
            const int o = c / 6, kc = LPOOL + (c % 6) * 2;
            *(unsigned*)(&As[o * LDK + kc]) = 0;
        }
        for (int c = tid; c < (NP - HID) * (KP / 2); c += 256) { // o-pad rows
            const int o = HID + c / (KP / 2), kc = (c % (KP / 2)) * 2;
            *(unsigned*)(&As[o * LDK + kc]) = 0;
        }
    }
    {
        const unsigned short* ys = ypool + ((size_t)u * BATCH + b0) * KP;
        for (int c = tid; c < BH * (KP / 8); c += 256) {
            const int n  = c / (KP / 8);
            const int kc = (c % (KP / 8)) * 8;
            *(short8*)(&Bs[n * LDK + kc]) = *(const short8*)(ys + n * KP + kc);
        }
    }
    if (tid < NP) {
        float4 cv = {0.f, 0.f, 0.f, 0.f};
        if (tid < HID) {
            const int uo = u * HID + tid;
            const float s = g2[uo] * rsqrtf(v2[uo] + EPS);
            cv.x = s;
            cv.y = (b2[uo] - m2[uo]) * s + be2[uo];
            cv.z = w3[uo];
        }
        cs4[tid] = cv;
    }
    __syncthreads();

    const int lane = tid & 63;
    const int wave = tid >> 6;
    const int col  = lane & 15;
    const int quad = lane >> 4;

    short8 bf_[2][3];
#pragma unroll
    for (int j = 0; j < 2; ++j) {
        const int brow = 16 * (2 * wave + j) + col;
#pragma unroll
        for (int s = 0; s < 3; ++s)
            bf_[j][s] = *(const short8*)(&Bs[brow * LDK + 32 * s + 8 * quad]);
    }

    float zp0 = 0.f, zp1 = 0.f;
#pragma unroll
    for (int mt = 0; mt < 7; ++mt) {
        short8 af[3];
#pragma unroll
        for (int s = 0; s < 3; ++s)
            af[s] = *(const short8*)(&As[(16 * mt + col) * LDK + 32 * s + 8 * quad]);

        float4v a0 = {0.f, 0.f, 0.f, 0.f}, a1 = {0.f, 0.f, 0.f, 0.f};
#pragma unroll
        for (int s = 0; s < 3; ++s) {
            a0 = __builtin_amdgcn_mfma_f32_16x16x32_bf16(af[s], bf_[0][s], a0, 0, 0, 0);
            a1 = __builtin_amdgcn_mfma_f32_16x16x32_bf16(af[s], bf_[1][s], a1, 0, 0, 0);
        }
#pragma unroll
        for (int r = 0; r < 4; ++r) {
            const float4 cv = cs4[16 * mt + 4 * quad + r];
            zp0 = fmaf(fmaxf(fmaf(a0[r], cv.x, cv.y), 0.f), cv.z, zp0);
            zp1 = fmaf(fmaxf(fmaf(a1[r], cv.x, cv.y), 0.f), cv.z, zp1);
        }
    }

    zp0 += __shfl_xor(zp0, 16); zp0 += __shfl_xor(zp0, 32);
    zp1 += __shfl_xor(zp1, 16); zp1 += __shfl_xor(zp1, 32);

    if (quad == 0) {
        const float s3 = g3[u] * rsqrtf(v3[u] + EPS);
        const float c3 = (b3[u] - m3[u]) * s3 + be3[u];
        const int bA = b0 + 16 * (2 * wave + 0) + col;
        const int bB = b0 + 16 * (2 * wave + 1) + col;
        zbuf[(size_t)u * BATCH + bA] = fmaxf(fmaf(zp0, s3, c3), 0.f);
        zbuf[(size_t)u * BATCH + bB] = fmaxf(fmaf(zp1, s3, c3), 0.f);
    }
}

// ---------------------------------------------------------------------------
// k_final: 300 -> 50.  (byte-identical to R3/R8/R9 — verified correct)
// ---------------------------------------------------------------------------
__global__ __launch_bounds__(256, 4)
void k_final(const float* __restrict__ zbuf, const float* __restrict__ wf,
             const float* __restrict__ bf, float* __restrict__ out)
{
    const int n = blockIdx.x;
    const int b = threadIdx.x;
    float a0 = 0.f, a1 = 0.f, a2 = 0.f, a3 = 0.f;
#pragma unroll 5
    for (int u = 0; u < NU; u += 4) {
        a0 = fmaf(zbuf[(size_t)(u + 0) * BATCH + b], wf[n * NU + u + 0], a0);
        a1 = fmaf(zbuf[(size_t)(u + 1) * BATCH + b], wf[n * NU + u + 1], a1);
        a2 = fmaf(zbuf[(size_t)(u + 2) * BATCH + b], wf[n * NU + u + 2], a2);
        a3 = fmaf(zbuf[(size_t)(u + 3) * BATCH + b], wf[n * NU + u + 3], a3);
    }
    out[(size_t)b * NCLS + n] = (a0 + a1) + (a2 + a3) + bf[n];
}

extern "C" void kernel_launch(void* const* d_in, const int* in_sizes, int n_in,
                              void* d_out, int out_size, void* d_ws, size_t ws_size,
                              hipStream_t stream)
{
    const float* x   = (const float*)d_in[0];
    const float* w1  = (const float*)d_in[1];
    const float* b1  = (const float*)d_in[2];
    const float* g1  = (const float*)d_in[3];
    const float* be1 = (const float*)d_in[4];
    const float* m1  = (const float*)d_in[5];
    const float* v1  = (const float*)d_in[6];
    const float* w2  = (const float*)d_in[7];
    const float* b2  = (const float*)d_in[8];
    const float* g2  = (const float*)d_in[9];
    const float* be2 = (const float*)d_in[10];
    const float* m2  = (const float*)d_in[11];
    const float* v2  = (const float*)d_in[12];
    const float* w3  = (const float*)d_in[13];
    const float* b3  = (const float*)d_in[14];
    const float* g3  = (const float*)d_in[15];
    const float* be3 = (const float*)d_in[16];
    const float* m3  = (const float*)d_in[17];
    const float* v3  = (const float*)d_in[18];
    const float* wf  = (const float*)d_in[19];
    const float* bf  = (const float*)d_in[20];

    // workspace layout (bytes):
    //   ypool  bf16 [300][256][96]  @ 0          (14,745,600)
    //   zbuf   f32  [300][256]      @ 14,745,600 (307,200)
    //   Wbh    bf16 [320][104]      @ 15,052,800 (66,560)
    //   Wbl    bf16 [320][104]      @ 15,119,360 (66,560)
    //   xc     u32  [256][4][608]   @ 15,185,920 (2,490,368)
    unsigned short* ypool = (unsigned short*)d_ws;
    float* zbuf = (float*)((char*)d_ws + 14745600);
    unsigned short* Wbh = (unsigned short*)((char*)d_ws + 15052800);
    unsigned short* Wbl = (unsigned short*)((char*)d_ws + 15119360);
    unsigned int*   xc  = (unsigned int*)((char*)d_ws + 15185920);

    const int prep_elems = WBROWS * WROW + BATCH * 4 * LIN;
    k_prep<<<(prep_elems + 255) / 256, 256, 0, stream>>>(w1, x, Wbh, Wbl, xc);

    dim3 gc(BATCH, 6);
    k_conv4<<<gc, 256, 0, stream>>>(Wbh, Wbl, xc, b1, g1, be1, m1, v1, ypool);

    dim3 gm(NU, BATCH / BH);
    k_mlp<<<gm, 256, 0, stream>>>(ypool, w2, b2, g2, be2, m2, v2,
                                  w3, b3, g3, be3, m3, v3, zbuf);

    k_final<<<NCLS, 256, 0, stream>>>(zbuf, wf, bf, (float*)d_out);
}